// Round 6
// baseline (150.202 us; speedup 1.0000x reference)
//
#include <hip/hip_runtime.h>
#include <stdint.h>

#define BN_ 8192
#define DK_ 256
#define LOG2E 1.4426950408889634f
#define LN2 0.6931471805599453f

typedef __attribute__((ext_vector_type(4))) float f32x4;
typedef __attribute__((ext_vector_type(8))) short short8;
typedef __attribute__((ext_vector_type(8))) __bf16 bf16x8;
typedef __attribute__((ext_vector_type(4))) unsigned short us4;

// RNE float -> bf16
__device__ __forceinline__ unsigned short f2bf(float f) {
  unsigned u = __float_as_uint(f);
  u = (u + 0x7fffu + ((u >> 16) & 1u)) >> 16;
  return (unsigned short)u;
}

// async global->LDS, 16B/lane; LDS dest wave-uniform base + lane*16, global src per-lane
#define GLD16(gp, lp)                                                   \
  __builtin_amdgcn_global_load_lds(                                     \
      (__attribute__((address_space(1))) void*)(gp),                    \
      (__attribute__((address_space(3))) void*)(lp), 16, 0, 0)

#define BAR() __builtin_amdgcn_s_barrier()
#define VM4() asm volatile("s_waitcnt vmcnt(4)" ::: "memory")
#define VM8() asm volatile("s_waitcnt vmcnt(8)" ::: "memory")

// ---------------- Kernel 1: row-normalize fp32 -> bf16 (h,l scaled by log2e) ----------------
__global__ __launch_bounds__(256) void norm_kernel(
    const float* __restrict__ hf, const float* __restrict__ lf,
    const float* __restrict__ af,
    unsigned short* __restrict__ hn, unsigned short* __restrict__ ln,
    unsigned short* __restrict__ an) {
  const int tid = threadIdx.x;
  const int w = tid >> 6, lane = tid & 63;
  const int grow = blockIdx.x * 4 + w;
  const int m = grow >> 13;
  const int r = grow & (BN_ - 1);
  const float* src = (m == 0) ? hf : (m == 1) ? lf : af;
  unsigned short* dst = (m == 0) ? hn : (m == 1) ? ln : an;
  const float4 v = ((const float4*)(src + (size_t)r * DK_))[lane];
  float ss = v.x * v.x + v.y * v.y + v.z * v.z + v.w * v.w;
#pragma unroll
  for (int mk = 32; mk >= 1; mk >>= 1) ss += __shfl_xor(ss, mk, 64);
  float inv = 1.0f / fmaxf(sqrtf(ss), 1e-8f);
  if (m != 2) inv *= LOG2E;
  us4 o;
  o.x = f2bf(v.x * inv);
  o.y = f2bf(v.y * inv);
  o.z = f2bf(v.z * inv);
  o.w = f2bf(v.w * inv);
  *(us4*)(dst + (size_t)r * DK_ + lane * 4) = o;
}

// ---------------- Kernel 2: fused GEMM + exp2-row-sum + diag ----------------
// A = [hn;ln] stacked [16384,256], B = an [8192,256], S = A·B^T.
// 256 blocks, 512 thr (8 waves 2Mx4N), tile 256x256, BK=64 (2 K-halves/step).
// LDS: 4-slot circular queue of K-half units (32KB, A16K+B16K interleaved, swizzled).
// TWO barriers per K-step only; vmcnt(4) gate before each; compiler interleaves
// ds_read<->MFMA via fine-grained lgkmcnt inside each barrier-free half.
__global__ __launch_bounds__(512, 2) void gemm_lse_kernel(
    const unsigned short* __restrict__ hl, const unsigned short* __restrict__ an,
    float* __restrict__ sumexp, float* __restrict__ diag) {
  extern __shared__ char lds[];  // 4 * 32KB = 128KB

  const int tid = threadIdx.x;
  const int lane = tid & 63, w = tid >> 6;
  const int wr = w >> 2, wc = w & 3;
  const int lmod = lane & 15, lhalf = lane >> 4;

  const int bid = blockIdx.x;
  const int swz = (bid & 7) * 32 + (bid >> 3);  // bijective on 256, XCD-grouping
  const int mt = swz >> 2;                      // row tile 0..63
  const int cg = swz & 3;                       // col group (8 tiles each)

  // ---- stage-side constants (same layout as R5, verified absmax=0) ----
  const int isB = ((lane >> 2) ^ (lane >> 5)) & 1;
  const int lcst = (lane & 3) ^ ((lane >> 3) & 3);
  const int rbase = w * 32 + (lane >> 3);
  const char* myBase =
      (isB ? (const char*)an : (const char*)hl + (size_t)mt * 131072) +
      (size_t)rbase * 512 + lcst * 16;
  char* ldsW = lds + w * 4096 + lane * 16;

  // ---- read-side constants ----
  const int xsw = 16 * (lhalf ^ (lmod & 3));
  const int aoff = wr * 16384 + lmod * 128 + 64 * ((lmod >> 2) & 1) + xsw;
  const int boff = wc * 8192 + lmod * 128 + 64 * (1 ^ ((lmod >> 2) & 1)) + xsw;

#define STAGE(uu)                                                        \
  do {                                                                   \
    const int u_ = (uu) & 63;                                            \
    const int kb_ = ((u_ >> 1) & 3) * 128 + (u_ & 1) * 64;               \
    const int nto_ = (cg * 8 + (u_ >> 3)) * 131072 + kb_;                \
    const char* s_ = myBase + (isB ? nto_ : kb_);                        \
    char* d_ = ldsW + ((uu) & 3) * 32768;                                \
    GLD16(s_, d_);                                                       \
    GLD16(s_ + 4096, d_ + 1024);                                         \
    GLD16(s_ + 8192, d_ + 2048);                                         \
    GLD16(s_ + 12288, d_ + 3072);                                        \
  } while (0)

#define LD8(dst, base, off)                                              \
  dst = __builtin_bit_cast(bf16x8, *(const short8*)((base) + (off)))

  float rsum[8][4];
#pragma unroll
  for (int m = 0; m < 8; ++m)
#pragma unroll
    for (int r = 0; r < 4; ++r) rsum[m][r] = 0.0f;

  // prologue: stage units 0..3 (fills all 4 slots); gate units 0,1; barrier
  STAGE(0);
  STAGE(1);
  STAGE(2);
  STAGE(3);
  VM8();
  BAR();

#pragma unroll 1
  for (int i = 0; i < 8; ++i) {
    f32x4 acc[8][4];
#pragma unroll
    for (int m = 0; m < 8; ++m)
#pragma unroll
      for (int n = 0; n < 4; ++n) acc[m][n] = f32x4{0.f, 0.f, 0.f, 0.f};

#pragma unroll
    for (int kt = 0; kt < 4; ++kt) {
      const int u = 2 * (i * 4 + kt);
      const char* L0 = lds + ((u & 3) * 32768);
      const char* L1 = lds + (((u + 1) & 3) * 32768);

      // ---- half 0: read L0 frags, MFMA ks0 (compiler interleaves via lgkmcnt) ----
      {
        bf16x8 af[8], bf[4];
#pragma unroll
        for (int m = 0; m < 8; ++m) LD8(af[m], L0, aoff + m * 2048);
#pragma unroll
        for (int n = 0; n < 4; ++n) LD8(bf[n], L0, boff + n * 2048);
        __builtin_amdgcn_s_setprio(1);
#pragma unroll
        for (int m = 0; m < 8; ++m)
#pragma unroll
          for (int n = 0; n < 4; ++n)
            acc[m][n] = __builtin_amdgcn_mfma_f32_16x16x32_bf16(af[m], bf[n], acc[m][n], 0, 0, 0);
        __builtin_amdgcn_s_setprio(0);
      }
      VM4();   // in-order retire => everything except newest stage landed
      BAR();   // all waves consumed (lgkm-drained) slot L0
      if (u + 4 < 64) STAGE(u + 4);   // overwrite L0's slot

      // ---- half 1: read L1 frags, MFMA ks1 ----
      {
        bf16x8 af[8], bf[4];
#pragma unroll
        for (int m = 0; m < 8; ++m) LD8(af[m], L1, aoff + m * 2048);
#pragma unroll
        for (int n = 0; n < 4; ++n) LD8(bf[n], L1, boff + n * 2048);
        __builtin_amdgcn_s_setprio(1);
#pragma unroll
        for (int m = 0; m < 8; ++m)
#pragma unroll
          for (int n = 0; n < 4; ++n)
            acc[m][n] = __builtin_amdgcn_mfma_f32_16x16x32_bf16(af[m], bf[n], acc[m][n], 0, 0, 0);
        __builtin_amdgcn_s_setprio(0);
      }
      VM4();
      BAR();   // all waves consumed slot L1; next pair (u+2,u+3) resident
      if (u + 5 < 64) STAGE(u + 5);   // overwrite L1's slot
    }

    // ---- tile epilogue: diag (rare) + exp2 into persistent rsum ----
    if (cg * 8 + i == (mt & 31)) {
#pragma unroll
      for (int m = 0; m < 8; ++m)
#pragma unroll
        for (int n = 0; n < 4; ++n)
#pragma unroll
          for (int r = 0; r < 4; ++r) {
            const int row_t = wr * 128 + m * 16 + lhalf * 4 + r;
            const int col_t = wc * 64 + n * 16 + lmod;
            if (row_t == col_t)
              diag[(mt >> 5) * BN_ + (mt & 31) * 256 + row_t] = acc[m][n][r] * LN2;
          }
    }
#pragma unroll
    for (int m = 0; m < 8; ++m)
#pragma unroll
      for (int n = 0; n < 4; ++n)
#pragma unroll
        for (int r = 0; r < 4; ++r) rsum[m][r] += exp2f(acc[m][n][r]);
  }

  // ---- final: reduce across 16 col-lanes, one atomic per row ----
#pragma unroll
  for (int m = 0; m < 8; ++m)
#pragma unroll
    for (int r = 0; r < 4; ++r) {
      float v = rsum[m][r];
      v += __shfl_xor(v, 1, 64);
      v += __shfl_xor(v, 2, 64);
      v += __shfl_xor(v, 4, 64);
      v += __shfl_xor(v, 8, 64);
      if (lmod == 0)
        atomicAdd(&sumexp[(mt >> 5) * BN_ + (mt & 31) * 256 + wr * 128 + m * 16 + lhalf * 4 + r], v);
    }
#undef STAGE
#undef LD8
}

// ---------------- Kernel 3: CE = mean(log(sumexp) - diag) ----------------
__global__ __launch_bounds__(1024) void finalize_kernel(
    const float* __restrict__ sumexp, const float* __restrict__ diag,
    float* __restrict__ out) {
  const int tid = threadIdx.x;
  float s = 0.0f;
  for (int i = tid; i < 2 * BN_; i += 1024) s += logf(sumexp[i]) - diag[i];
#pragma unroll
  for (int mk = 32; mk >= 1; mk >>= 1) s += __shfl_xor(s, mk, 64);
  __shared__ float red[16];
  if ((tid & 63) == 0) red[tid >> 6] = s;
  __syncthreads();
  if (tid == 0) {
    float t = 0.f;
#pragma unroll
    for (int j = 0; j < 16; ++j) t += red[j];
    out[0] = t * (1.0f / (float)BN_);
  }
}

extern "C" void kernel_launch(void* const* d_in, const int* in_sizes, int n_in,
                              void* d_out, int out_size, void* d_ws, size_t ws_size,
                              hipStream_t stream) {
  const float* hf = (const float*)d_in[0];
  const float* lf = (const float*)d_in[1];
  const float* af = (const float*)d_in[2];

  char* ws = (char*)d_ws;
  const size_t nmat = (size_t)BN_ * DK_;
  unsigned short* hn = (unsigned short*)ws;          // 4 MB (hn,ln contiguous = stacked A)
  unsigned short* ln = hn + nmat;                    // 4 MB
  unsigned short* an = ln + nmat;                    // 4 MB
  float* sumexp = (float*)(ws + 3 * nmat * sizeof(unsigned short));  // 64 KB
  float* diag = sumexp + 2 * BN_;                                    // 64 KB

  hipFuncSetAttribute((const void*)gemm_lse_kernel,
                      hipFuncAttributeMaxDynamicSharedMemorySize, 131072);

  hipMemsetAsync(sumexp, 0, 2 * BN_ * sizeof(float), stream);
  norm_kernel<<<(3 * BN_) / 4, 256, 0, stream>>>(hf, lf, af, hn, ln, an);
  gemm_lse_kernel<<<256, 512, 131072, stream>>>(hn, an, sumexp, diag);
  finalize_kernel<<<1, 1024, 0, stream>>>(sumexp, diag, (float*)d_out);
}

// Round 10
// 106.648 us; speedup vs baseline: 1.4084x; 1.4084x over previous
//
#include <hip/hip_runtime.h>
#include <stdint.h>

#define BN_ 8192
#define DK_ 256
#define LOG2E 1.4426950408889634f
#define LN2 0.6931471805599453f

typedef __attribute__((ext_vector_type(4))) float f32x4;
typedef __attribute__((ext_vector_type(8))) short short8;
typedef __attribute__((ext_vector_type(8))) __bf16 bf16x8;
typedef __attribute__((ext_vector_type(4))) unsigned short us4;

// RNE float -> bf16
__device__ __forceinline__ unsigned short f2bf(float f) {
  unsigned u = __float_as_uint(f);
  u = (u + 0x7fffu + ((u >> 16) & 1u)) >> 16;
  return (unsigned short)u;
}

// async global->LDS, 16B/lane; LDS dest wave-uniform base + lane*16, global src per-lane
#define GLD16(gp, lp)                                                   \
  __builtin_amdgcn_global_load_lds(                                     \
      (__attribute__((address_space(1))) void*)(gp),                    \
      (__attribute__((address_space(3))) void*)(lp), 16, 0, 0)

#define BAR() __builtin_amdgcn_s_barrier()
#define VM8() asm volatile("s_waitcnt vmcnt(8)" ::: "memory")
#define VM4() asm volatile("s_waitcnt vmcnt(4)" ::: "memory")
#define VM0() asm volatile("s_waitcnt vmcnt(0)" ::: "memory")

// ---------------- Kernel 1: row-normalize fp32 -> bf16 (h,l scaled by log2e) ----------------
__global__ __launch_bounds__(256) void norm_kernel(
    const float* __restrict__ hf, const float* __restrict__ lf,
    const float* __restrict__ af,
    unsigned short* __restrict__ hn, unsigned short* __restrict__ ln,
    unsigned short* __restrict__ an) {
  const int tid = threadIdx.x;
  const int w = tid >> 6, lane = tid & 63;
  const int grow = blockIdx.x * 4 + w;
  const int m = grow >> 13;
  const int r = grow & (BN_ - 1);
  const float* src = (m == 0) ? hf : (m == 1) ? lf : af;
  unsigned short* dst = (m == 0) ? hn : (m == 1) ? ln : an;
  const float4 v = ((const float4*)(src + (size_t)r * DK_))[lane];
  float ss = v.x * v.x + v.y * v.y + v.z * v.z + v.w * v.w;
#pragma unroll
  for (int mk = 32; mk >= 1; mk >>= 1) ss += __shfl_xor(ss, mk, 64);
  float inv = 1.0f / fmaxf(sqrtf(ss), 1e-8f);
  if (m != 2) inv *= LOG2E;
  us4 o;
  o.x = f2bf(v.x * inv);
  o.y = f2bf(v.y * inv);
  o.z = f2bf(v.z * inv);
  o.w = f2bf(v.w * inv);
  *(us4*)(dst + (size_t)r * DK_ + lane * 4) = o;
}

// ---------------- Kernel 2: fused GEMM + exp2-row-sum + diag ----------------
// A = [hn;ln] stacked [16384,256], B = an [8192,256], S = A·B^T.
// 256 blocks, 512 thr (8 waves 2Mx4N), tile 256x256, units of BK=32.
// LDS: 4-slot circular queue (32KB/slot, A16K+B16K interleaved, XOR-swizzled).
// Unit body: {STAGE(u+2); vmcnt gate; BARRIER; read slot u; MFMA}.
// Row-sum epilogue MUST accumulate across the 4 wc-waves (same rows,
// different 64-col slices) AND the 4 cg-blocks -> atomicAdd (R7/R9's plain
// per-cg store dropped 3/4 of each row sum: absmax 2.75 = 2*ln(4)).
__global__ __launch_bounds__(512, 2) void gemm_lse_kernel(
    const unsigned short* __restrict__ hl, const unsigned short* __restrict__ an,
    float* __restrict__ sumexp /*[16384]*/, float* __restrict__ diag /*[16384]*/) {
  extern __shared__ char lds[];  // 4 * 32KB = 128KB

  const int tid = threadIdx.x;
  const int lane = tid & 63, w = tid >> 6;
  const int wr = w >> 2, wc = w & 3;
  const int lmod = lane & 15, lhalf = lane >> 4;

  const int bid = blockIdx.x;
  const int swz = (bid & 7) * 32 + (bid >> 3);  // bijective on 256, XCD-grouping
  const int mt = swz >> 2;                      // row tile 0..63
  const int cg = swz & 3;                       // col group (8 tiles each)

  // ---- stage-side constants (layout verified absmax=0 in R3/R5/R6) ----
  const int isB = ((lane >> 2) ^ (lane >> 5)) & 1;
  const int lcst = (lane & 3) ^ ((lane >> 3) & 3);
  const int rbase = w * 32 + (lane >> 3);
  const char* myBase =
      (isB ? (const char*)an : (const char*)hl + (size_t)mt * 131072) +
      (size_t)rbase * 512 + lcst * 16;
  char* ldsW = lds + w * 4096 + lane * 16;

  // ---- read-side constants ----
  const int xsw = 16 * (lhalf ^ (lmod & 3));
  const int aoff = wr * 16384 + lmod * 128 + 64 * ((lmod >> 2) & 1) + xsw;
  const int boff = wc * 8192 + lmod * 128 + 64 * (1 ^ ((lmod >> 2) & 1)) + xsw;

#define STAGE(uu)                                                        \
  do {                                                                   \
    const int u_ = (uu) & 63;                                            \
    const int kb_ = ((u_ >> 1) & 3) * 128 + (u_ & 1) * 64;               \
    const int nto_ = (cg * 8 + (u_ >> 3)) * 131072 + kb_;                \
    const char* s_ = myBase + (isB ? nto_ : kb_);                        \
    char* d_ = ldsW + ((uu) & 3) * 32768;                                \
    GLD16(s_, d_);                                                       \
    GLD16(s_ + 4096, d_ + 1024);                                         \
    GLD16(s_ + 8192, d_ + 2048);                                         \
    GLD16(s_ + 12288, d_ + 3072);                                        \
  } while (0)

#define LD8(dst, base, off)                                              \
  dst = __builtin_bit_cast(bf16x8, *(const short8*)((base) + (off)))

  float rsum[8][4];
#pragma unroll
  for (int m = 0; m < 8; ++m)
#pragma unroll
    for (int r = 0; r < 4; ++r) rsum[m][r] = 0.0f;

  // prologue: fill pipeline 2 deep (8 loads in flight)
  STAGE(0);
  STAGE(1);

#pragma unroll 1
  for (int i = 0; i < 8; ++i) {
    f32x4 acc[8][4];
#pragma unroll
    for (int m = 0; m < 8; ++m)
#pragma unroll
      for (int n = 0; n < 4; ++n) acc[m][n] = f32x4{0.f, 0.f, 0.f, 0.f};

#pragma unroll
    for (int uu = 0; uu < 8; ++uu) {
      const int u = i * 8 + uu;
      // WAR: STAGE(u+2) overwrites slot (u-2)&3; every wave passed the
      // unit-(u-1) barrier, which lies after its slot-(u-2) reads.
      if (u + 2 < 64) {
        STAGE(u + 2);
        VM8();  // my 2 newest stages (u+1,u+2) may fly; STAGE(u) retired
      } else if (u == 62) {
        VM4();  // only STAGE(63) may remain in flight
      } else {
        VM0();  // u == 63
      }
      BAR();    // collective: ALL waves' STAGE(u) landed -> slot u readable
      const char* L = lds + ((u & 3) * 32768);

      bf16x8 bf[4], af0[4], af1[4];
#pragma unroll
      for (int n = 0; n < 4; ++n) LD8(bf[n], L, boff + n * 2048);
#pragma unroll
      for (int m = 0; m < 4; ++m) LD8(af0[m], L, aoff + m * 2048);
      __builtin_amdgcn_s_setprio(1);
#pragma unroll
      for (int m = 0; m < 4; ++m)
#pragma unroll
        for (int n = 0; n < 4; ++n)
          acc[m][n] = __builtin_amdgcn_mfma_f32_16x16x32_bf16(af0[m], bf[n], acc[m][n], 0, 0, 0);
      __builtin_amdgcn_s_setprio(0);
#pragma unroll
      for (int m = 0; m < 4; ++m) LD8(af1[m], L, aoff + (m + 4) * 2048);
      __builtin_amdgcn_s_setprio(1);
#pragma unroll
      for (int m = 0; m < 4; ++m)
#pragma unroll
        for (int n = 0; n < 4; ++n)
          acc[m + 4][n] = __builtin_amdgcn_mfma_f32_16x16x32_bf16(af1[m], bf[n], acc[m + 4][n], 0, 0, 0);
      __builtin_amdgcn_s_setprio(0);
    }

    // ---- tile epilogue: diag (rare) + exp2 into persistent rsum ----
    if (cg * 8 + i == (mt & 31)) {
#pragma unroll
      for (int m = 0; m < 8; ++m)
#pragma unroll
        for (int n = 0; n < 4; ++n)
#pragma unroll
          for (int r = 0; r < 4; ++r) {
            const int row_t = wr * 128 + m * 16 + lhalf * 4 + r;
            const int col_t = wc * 64 + n * 16 + lmod;
            if (row_t == col_t)
              diag[(mt >> 5) * BN_ + (mt & 31) * 256 + row_t] = acc[m][n][r] * LN2;
          }
    }
#pragma unroll
    for (int m = 0; m < 8; ++m)
#pragma unroll
      for (int n = 0; n < 4; ++n)
#pragma unroll
        for (int r = 0; r < 4; ++r) rsum[m][r] += exp2f(acc[m][n][r]);
  }

  // ---- final: reduce across 16 col-lanes, then atomicAdd (sums wc-waves
  // within the block AND the 4 cg-blocks per row) ----
#pragma unroll
  for (int m = 0; m < 8; ++m)
#pragma unroll
    for (int r = 0; r < 4; ++r) {
      float v = rsum[m][r];
      v += __shfl_xor(v, 1, 64);
      v += __shfl_xor(v, 2, 64);
      v += __shfl_xor(v, 4, 64);
      v += __shfl_xor(v, 8, 64);
      if (lmod == 0)
        atomicAdd(&sumexp[(mt >> 5) * BN_ + (mt & 31) * 256 + wr * 128 + m * 16 + lhalf * 4 + r], v);
    }
#undef STAGE
#undef LD8
}

// ---------------- Kernel 3: CE = mean(log(sumexp) - diag) ----------------
__global__ __launch_bounds__(1024) void finalize_kernel(
    const float* __restrict__ sumexp, const float* __restrict__ diag,
    float* __restrict__ out) {
  const int tid = threadIdx.x;
  float s = 0.0f;
  for (int i = tid; i < 2 * BN_; i += 1024) s += logf(sumexp[i]) - diag[i];
#pragma unroll
  for (int mk = 32; mk >= 1; mk >>= 1) s += __shfl_xor(s, mk, 64);
  __shared__ float red[16];
  if ((tid & 63) == 0) red[tid >> 6] = s;
  __syncthreads();
  if (tid == 0) {
    float t = 0.f;
#pragma unroll
    for (int j = 0; j < 16; ++j) t += red[j];
    out[0] = t * (1.0f / (float)BN_);
  }
}

extern "C" void kernel_launch(void* const* d_in, const int* in_sizes, int n_in,
                              void* d_out, int out_size, void* d_ws, size_t ws_size,
                              hipStream_t stream) {
  const float* hf = (const float*)d_in[0];
  const float* lf = (const float*)d_in[1];
  const float* af = (const float*)d_in[2];

  char* ws = (char*)d_ws;
  const size_t nmat = (size_t)BN_ * DK_;
  unsigned short* hn = (unsigned short*)ws;          // 4 MB (hn,ln contiguous = stacked A)
  unsigned short* ln = hn + nmat;                    // 4 MB
  unsigned short* an = ln + nmat;                    // 4 MB
  float* sumexp = (float*)(ws + 3 * nmat * sizeof(unsigned short));  // 64 KB [16384]
  float* diag = sumexp + 2 * BN_;                                    // 64 KB [16384]

  hipFuncSetAttribute((const void*)gemm_lse_kernel,
                      hipFuncAttributeMaxDynamicSharedMemorySize, 131072);

  hipMemsetAsync(sumexp, 0, 2 * BN_ * sizeof(float), stream);
  norm_kernel<<<(3 * BN_) / 4, 256, 0, stream>>>(hf, lf, af, hn, ln, an);
  gemm_lse_kernel<<<256, 512, 131072, stream>>>(hn, an, sumexp, diag);
  finalize_kernel<<<1, 1024, 0, stream>>>(sumexp, diag, (float*)d_out);
}

// Round 11
// 93.868 us; speedup vs baseline: 1.6001x; 1.1361x over previous
//
#include <hip/hip_runtime.h>
#include <stdint.h>

#define BN_ 8192
#define DK_ 256
#define LOG2E 1.4426950408889634f
#define LN2 0.6931471805599453f

typedef __attribute__((ext_vector_type(4))) float f32x4;
typedef __attribute__((ext_vector_type(8))) short short8;
typedef __attribute__((ext_vector_type(8))) __bf16 bf16x8;
typedef __attribute__((ext_vector_type(4))) unsigned short us4;

// RNE float -> bf16
__device__ __forceinline__ unsigned short f2bf(float f) {
  unsigned u = __float_as_uint(f);
  u = (u + 0x7fffu + ((u >> 16) & 1u)) >> 16;
  return (unsigned short)u;
}

// async global->LDS, 16B/lane; LDS dest wave-uniform base + lane*16, global src per-lane
#define GLD16(gp, lp)                                                   \
  __builtin_amdgcn_global_load_lds(                                     \
      (__attribute__((address_space(1))) void*)(gp),                    \
      (__attribute__((address_space(3))) void*)(lp), 16, 0, 0)

#define BAR() __builtin_amdgcn_s_barrier()
#define VM8() asm volatile("s_waitcnt vmcnt(8)" ::: "memory")
#define VM4() asm volatile("s_waitcnt vmcnt(4)" ::: "memory")
#define VM0() asm volatile("s_waitcnt vmcnt(0)" ::: "memory")

// ---------------- Kernel 1: row-normalize fp32 -> bf16 (h,l scaled by log2e) ----------------
__global__ __launch_bounds__(256) void norm_kernel(
    const float* __restrict__ hf, const float* __restrict__ lf,
    const float* __restrict__ af,
    unsigned short* __restrict__ hn, unsigned short* __restrict__ ln,
    unsigned short* __restrict__ an) {
  const int tid = threadIdx.x;
  const int w = tid >> 6, lane = tid & 63;
  const int grow = blockIdx.x * 4 + w;
  const int m = grow >> 13;
  const int r = grow & (BN_ - 1);
  const float* src = (m == 0) ? hf : (m == 1) ? lf : af;
  unsigned short* dst = (m == 0) ? hn : (m == 1) ? ln : an;
  const float4 v = ((const float4*)(src + (size_t)r * DK_))[lane];
  float ss = v.x * v.x + v.y * v.y + v.z * v.z + v.w * v.w;
#pragma unroll
  for (int mk = 32; mk >= 1; mk >>= 1) ss += __shfl_xor(ss, mk, 64);
  float inv = 1.0f / fmaxf(sqrtf(ss), 1e-8f);
  if (m != 2) inv *= LOG2E;
  us4 o;
  o.x = f2bf(v.x * inv);
  o.y = f2bf(v.y * inv);
  o.z = f2bf(v.z * inv);
  o.w = f2bf(v.w * inv);
  *(us4*)(dst + (size_t)r * DK_ + lane * 4) = o;
}

// ---------------- Kernel 2: fused GEMM + exp2-row-sum + diag ----------------
// A = [hn;ln] stacked [16384,256], B = an [8192,256], S = A·B^T.
// 256 blocks, 512 thr (8 waves 2Mx4N), tile 256x256, units of BK=32.
// LDS: 4-slot circular queue (32KB/slot, A16K+B16K interleaved, XOR-swizzled).
// Unit body: {STAGE(u+2); vmcnt gate; BARRIER; read slot u; MFMA}.
// exp2 via __builtin_amdgcn_exp2f (single v_exp_f32) -- plain exp2f lowers to
// the OCML expansion (~10 instrs + temps) and was 40% VALUBusy in R10.
__global__ __launch_bounds__(512, 2) void gemm_lse_kernel(
    const unsigned short* __restrict__ hl, const unsigned short* __restrict__ an,
    float* __restrict__ sumexp /*[16384]*/, float* __restrict__ diag /*[16384]*/) {
  extern __shared__ char lds[];  // 4 * 32KB = 128KB

  const int tid = threadIdx.x;
  const int lane = tid & 63, w = tid >> 6;
  const int wr = w >> 2, wc = w & 3;
  const int lmod = lane & 15, lhalf = lane >> 4;

  const int bid = blockIdx.x;
  const int swz = (bid & 7) * 32 + (bid >> 3);  // bijective on 256, XCD-grouping
  const int mt = swz >> 2;                      // row tile 0..63
  const int cg = swz & 3;                       // col group (8 tiles each)

  // ---- stage-side constants (layout verified absmax=0 in R3/R5/R10) ----
  const int isB = ((lane >> 2) ^ (lane >> 5)) & 1;
  const int lcst = (lane & 3) ^ ((lane >> 3) & 3);
  const int rbase = w * 32 + (lane >> 3);
  const char* myBase =
      (isB ? (const char*)an : (const char*)hl + (size_t)mt * 131072) +
      (size_t)rbase * 512 + lcst * 16;
  char* ldsW = lds + w * 4096 + lane * 16;

  // ---- read-side constants ----
  const int xsw = 16 * (lhalf ^ (lmod & 3));
  const int aoff = wr * 16384 + lmod * 128 + 64 * ((lmod >> 2) & 1) + xsw;
  const int boff = wc * 8192 + lmod * 128 + 64 * (1 ^ ((lmod >> 2) & 1)) + xsw;

#define STAGE(uu)                                                        \
  do {                                                                   \
    const int u_ = (uu) & 63;                                            \
    const int kb_ = ((u_ >> 1) & 3) * 128 + (u_ & 1) * 64;               \
    const int nto_ = (cg * 8 + (u_ >> 3)) * 131072 + kb_;                \
    const char* s_ = myBase + (isB ? nto_ : kb_);                        \
    char* d_ = ldsW + ((uu) & 3) * 32768;                                \
    GLD16(s_, d_);                                                       \
    GLD16(s_ + 4096, d_ + 1024);                                         \
    GLD16(s_ + 8192, d_ + 2048);                                         \
    GLD16(s_ + 12288, d_ + 3072);                                        \
  } while (0)

#define LD8(dst, base, off)                                              \
  dst = __builtin_bit_cast(bf16x8, *(const short8*)((base) + (off)))

  float rsum[8][4];
#pragma unroll
  for (int m = 0; m < 8; ++m)
#pragma unroll
    for (int r = 0; r < 4; ++r) rsum[m][r] = 0.0f;

  // prologue: fill pipeline 2 deep (8 loads in flight)
  STAGE(0);
  STAGE(1);

#pragma unroll 1
  for (int i = 0; i < 8; ++i) {
    f32x4 acc[8][4];
#pragma unroll
    for (int m = 0; m < 8; ++m)
#pragma unroll
      for (int n = 0; n < 4; ++n) acc[m][n] = f32x4{0.f, 0.f, 0.f, 0.f};

#pragma unroll
    for (int uu = 0; uu < 8; ++uu) {
      const int u = i * 8 + uu;
      // WAR: STAGE(u+2) overwrites slot (u-2)&3; every wave passed the
      // unit-(u-1) barrier, which lies after its slot-(u-2) reads.
      if (u + 2 < 64) {
        STAGE(u + 2);
        VM8();  // my 2 newest stages (u+1,u+2) may fly; STAGE(u) retired
      } else if (u == 62) {
        VM4();  // only STAGE(63) may remain in flight
      } else {
        VM0();  // u == 63
      }
      BAR();    // collective: ALL waves' STAGE(u) landed -> slot u readable
      const char* L = lds + ((u & 3) * 32768);

      bf16x8 bf[4], af0[4], af1[4];
#pragma unroll
      for (int n = 0; n < 4; ++n) LD8(bf[n], L, boff + n * 2048);
#pragma unroll
      for (int m = 0; m < 4; ++m) LD8(af0[m], L, aoff + m * 2048);
      __builtin_amdgcn_s_setprio(1);
#pragma unroll
      for (int m = 0; m < 4; ++m)
#pragma unroll
        for (int n = 0; n < 4; ++n)
          acc[m][n] = __builtin_amdgcn_mfma_f32_16x16x32_bf16(af0[m], bf[n], acc[m][n], 0, 0, 0);
      __builtin_amdgcn_s_setprio(0);
#pragma unroll
      for (int m = 0; m < 4; ++m) LD8(af1[m], L, aoff + (m + 4) * 2048);
      __builtin_amdgcn_s_setprio(1);
#pragma unroll
      for (int m = 0; m < 4; ++m)
#pragma unroll
        for (int n = 0; n < 4; ++n)
          acc[m + 4][n] = __builtin_amdgcn_mfma_f32_16x16x32_bf16(af1[m], bf[n], acc[m + 4][n], 0, 0, 0);
      __builtin_amdgcn_s_setprio(0);
    }

    // ---- tile epilogue: diag (rare) + exp2 into persistent rsum ----
    if (cg * 8 + i == (mt & 31)) {
#pragma unroll
      for (int m = 0; m < 8; ++m)
#pragma unroll
        for (int n = 0; n < 4; ++n)
#pragma unroll
          for (int r = 0; r < 4; ++r) {
            const int row_t = wr * 128 + m * 16 + lhalf * 4 + r;
            const int col_t = wc * 64 + n * 16 + lmod;
            if (row_t == col_t)
              diag[(mt >> 5) * BN_ + (mt & 31) * 256 + row_t] = acc[m][n][r] * LN2;
          }
    }
#pragma unroll
    for (int m = 0; m < 8; ++m)
#pragma unroll
      for (int n = 0; n < 4; ++n)
#pragma unroll
        for (int r = 0; r < 4; ++r)
          rsum[m][r] += __builtin_amdgcn_exp2f(acc[m][n][r]);
  }

  // ---- final: reduce across 16 col-lanes, then atomicAdd (sums wc-waves
  // within the block AND the 4 cg-blocks per row) ----
#pragma unroll
  for (int m = 0; m < 8; ++m)
#pragma unroll
    for (int r = 0; r < 4; ++r) {
      float v = rsum[m][r];
      v += __shfl_xor(v, 1, 64);
      v += __shfl_xor(v, 2, 64);
      v += __shfl_xor(v, 4, 64);
      v += __shfl_xor(v, 8, 64);
      if (lmod == 0)
        atomicAdd(&sumexp[(mt >> 5) * BN_ + (mt & 31) * 256 + wr * 128 + m * 16 + lhalf * 4 + r], v);
    }
#undef STAGE
#undef LD8
}

// ---------------- Kernel 3: CE = mean(log(sumexp) - diag) ----------------
__global__ __launch_bounds__(1024) void finalize_kernel(
    const float* __restrict__ sumexp, const float* __restrict__ diag,
    float* __restrict__ out) {
  const int tid = threadIdx.x;
  float s = 0.0f;
  for (int i = tid; i < 2 * BN_; i += 1024) s += logf(sumexp[i]) - diag[i];
#pragma unroll
  for (int mk = 32; mk >= 1; mk >>= 1) s += __shfl_xor(s, mk, 64);
  __shared__ float red[16];
  if ((tid & 63) == 0) red[tid >> 6] = s;
  __syncthreads();
  if (tid == 0) {
    float t = 0.f;
#pragma unroll
    for (int j = 0; j < 16; ++j) t += red[j];
    out[0] = t * (1.0f / (float)BN_);
  }
}

extern "C" void kernel_launch(void* const* d_in, const int* in_sizes, int n_in,
                              void* d_out, int out_size, void* d_ws, size_t ws_size,
                              hipStream_t stream) {
  const float* hf = (const float*)d_in[0];
  const float* lf = (const float*)d_in[1];
  const float* af = (const float*)d_in[2];

  char* ws = (char*)d_ws;
  const size_t nmat = (size_t)BN_ * DK_;
  unsigned short* hn = (unsigned short*)ws;          // 4 MB (hn,ln contiguous = stacked A)
  unsigned short* ln = hn + nmat;                    // 4 MB
  unsigned short* an = ln + nmat;                    // 4 MB
  float* sumexp = (float*)(ws + 3 * nmat * sizeof(unsigned short));  // 64 KB [16384]
  float* diag = sumexp + 2 * BN_;                                    // 64 KB [16384]

  hipFuncSetAttribute((const void*)gemm_lse_kernel,
                      hipFuncAttributeMaxDynamicSharedMemorySize, 131072);

  hipMemsetAsync(sumexp, 0, 2 * BN_ * sizeof(float), stream);
  norm_kernel<<<(3 * BN_) / 4, 256, 0, stream>>>(hf, lf, af, hn, ln, an);
  gemm_lse_kernel<<<256, 512, 131072, stream>>>(hn, an, sumexp, diag);
  finalize_kernel<<<1, 1024, 0, stream>>>(sumexp, diag, (float*)d_out);
}